// Round 9
// baseline (86.544 us; speedup 1.0000x reference)
//
#include <hip/hip_runtime.h>
#include <hip/hip_fp16.h>
#include <math.h>

#define IMG_H 512
#define IMG_W 512
#define NIMG  16
#define HW    (IMG_H * IMG_W)

#define TH 16
#define TW 64
#define HTH (TH + 2)          // 18 halo rows (pair planes)
#define HTW (TW + 2)          // 66 halo cols
#define ERH (TH + 4)          // 20 en-ring rows
#define ERW (TW + 4)          // 68 en-ring cols
#define SP  72                // stride (half2 units) for ALL planes; 288 B/row
#define PADP 4                // left pad (half2 units) -> b128 bases 16B-aligned
#define TILES_H (IMG_H / TH)  // 32
#define TILES_W (IMG_W / TW)  // 8

typedef float vfloat4 __attribute__((ext_vector_type(4)));

__device__ __forceinline__ float rcp_fast(float v) {
#if __has_builtin(__builtin_amdgcn_rcpf)
    return __builtin_amdgcn_rcpf(v);
#else
    return 1.0f / v;
#endif
}
__device__ __forceinline__ float rsq_fast(float v) {
#if __has_builtin(__builtin_amdgcn_rsqf)
    return __builtin_amdgcn_rsqf(v);
#else
    return rsqrtf(v);
#endif
}
__device__ __forceinline__ float sqrt_fast(float v) {
#if __has_builtin(__builtin_amdgcn_sqrtf)
    return __builtin_amdgcn_sqrtf(v);
#else
    return sqrtf(v);
#endif
}

// atan2 via polynomial; |err| ~1e-4 rad (abs threshold is 0.66).
__device__ __forceinline__ float fast_atan2f(float y, float x) {
    float ay = fabsf(y), ax = fabsf(x);
    float mx = fmaxf(ay, ax), mn = fminf(ay, ax);
    float a = mn * rcp_fast(mx);
    float s = a * a;
    float r = fmaf(fmaf(fmaf(0.0208351f, s, -0.085133f), s, 0.180141f), s, -0.3302995f);
    r = a * fmaf(r, s, 0.9998660f);
    if (ay > ax)  r = 1.57079632679f - r;
    if (x < 0.0f) r = 3.14159265359f - r;
    return copysignf(r, y);
}

// Load 8 consecutive half2 (16B-aligned) -> 8 "x" floats and 8 "y" floats.
__device__ __forceinline__ void loadrow8(const __half2* p, float* a, float* b) {
    union { vfloat4 v; __half2 h[4]; } u0, u1;
    u0.v = *reinterpret_cast<const vfloat4*>(p);
    u1.v = *reinterpret_cast<const vfloat4*>(p + 4);
#pragma unroll
    for (int j = 0; j < 4; ++j) {
        float2 f = __half22float2(u0.h[j]);
        a[j] = f.x; b[j] = f.y;
    }
#pragma unroll
    for (int j = 0; j < 4; ++j) {
        float2 f = __half22float2(u1.h[j]);
        a[4 + j] = f.x; b[4 + j] = f.y;
    }
}

// 6-wide rows -> 4 Sobel magnitudes.
__device__ __forceinline__ vfloat4 sobel4(const float* tt, const float* mm, const float* bb) {
    float vs[6], dd[6];
#pragma unroll
    for (int j = 0; j < 6; ++j) {
        vs[j] = tt[j] + fmaf(2.0f, mm[j], bb[j]);   // vertical [1,2,1] for gx
        dd[j] = bb[j] - tt[j];                       // vertical [-1,0,1] for gy
    }
    vfloat4 mag;
    float gx, gy;
    gx = vs[2] - vs[0]; gy = fmaf(2.f, dd[1], dd[0] + dd[2]);
    mag.x = sqrt_fast(fmaf(gx, gx, gy * gy));
    gx = vs[3] - vs[1]; gy = fmaf(2.f, dd[2], dd[1] + dd[3]);
    mag.y = sqrt_fast(fmaf(gx, gx, gy * gy));
    gx = vs[4] - vs[2]; gy = fmaf(2.f, dd[3], dd[2] + dd[4]);
    mag.z = sqrt_fast(fmaf(gx, gx, gy * gy));
    gx = vs[5] - vs[3]; gy = fmaf(2.f, dd[4], dd[3] + dd[5]);
    mag.w = sqrt_fast(fmaf(gx, gx, gy * gy));
    return mag;
}

__device__ __forceinline__ vfloat4 mk4(const float* m) {
    vfloat4 v; v.x = m[1]; v.y = m[2]; v.z = m[3]; v.w = m[4]; return v;
}

__global__ __launch_bounds__(256, 7) void fused_kernel(const float* __restrict__ x,
                                                       float* __restrict__ out) {
    // All planes interleaved half2, stride 72 half2 (288 B):
    //   lden: {en0,en1} on 20x68 ring  = 20*72*4 = 5760 B
    //   pe:   {e0,e1}   on 18x66 halo  = 18*72*4 = 5184 B
    //   pad2: {ang,dl}                 = 5184 B
    //   psm:  {smax,smin}              = 5184 B      total 21312 B -> 7 blocks/CU
    __shared__ __align__(16) __half2 lden[ERH * SP];
    __shared__ __align__(16) __half2 pe  [HTH * SP];
    __shared__ __align__(16) __half2 pad2[HTH * SP];
    __shared__ __align__(16) __half2 psm [HTH * SP];

    // XCD-contiguous swizzle: 4096 blocks % 8 XCDs == 0 -> bijective.
    int bid0 = blockIdx.x;
    int bid  = (bid0 & 7) * (NIMG * TILES_H * TILES_W / 8) + (bid0 >> 3);

    int n   = bid / (TILES_H * TILES_W);
    int t   = bid - n * (TILES_H * TILES_W);
    int th  = t / TILES_W;
    int tw  = t - th * TILES_W;
    int h0  = th * TH;
    int w0  = tw * TW;

    const float* xb = x + (size_t)n * 3 * HW;
    int tid = threadIdx.x;

    // ---- A1: en over the 20x68 ring; e/ang/dl planes over 18x66 ----
    for (int i = tid; i < ERH * ERW; i += 256) {
        int er = i / ERW;
        int ec = i - er * ERW;
        int h  = h0 + er - 2;
        int w  = w0 + ec - 2;
        bool inimg = (h >= 0) && (h < IMG_H) && (w >= 0) && (w < IMG_W);
        int rem = h * IMG_W + w;

        float e0 = 0.f, e1 = 0.f, en0 = 0.f, en1 = 0.f;
        if (inimg) {
            e0 = xb[rem];
            e1 = xb[HW + rem];
            float is = rsq_fast(fmaf(e0, e0, e1 * e1));
            en0 = e0 * is;
            en1 = e1 * is;
        }
        lden[er * SP + ec + PADP] = __floats2half2_rn(en0, en1);

        int hr = er - 1, wc = ec - 1;
        if (hr >= 0 && hr < HTH && wc >= 0 && wc < HTW) {
            float dl = 0.f, ang = 0.f;
            if (inimg) {
                dl  = xb[2 * HW + rem];
                ang = 0.5f * fast_atan2f(e0, e1);
            }
            pe  [hr * SP + wc + PADP] = __floats2half2_rn(e0, e1);
            pad2[hr * SP + wc + PADP] = __floats2half2_rn(ang, dl);
        }
    }
    __syncthreads();

    // ---- A2: neighbor similarity (smax/smin) from the en plane ----
    for (int i = tid; i < HTH * HTW; i += 256) {
        int hr = i / HTW;
        int wc = i - hr * HTW;
        int eb = (hr + 1) * SP + (wc + 1) + PADP;

        float2 o  = __half22float2(lden[eb]);
        float2 u  = __half22float2(lden[eb + SP]);   // h+1
        float2 d  = __half22float2(lden[eb - SP]);   // h-1
        float2 lf = __half22float2(lden[eb + 1]);    // w+1
        float2 rg = __half22float2(lden[eb - 1]);    // w-1

        float dpu = fmaf(o.x, u.x,  o.y * u.y);
        float dpd = fmaf(o.x, d.x,  o.y * d.y);
        float dpl = fmaf(o.x, lf.x, o.y * lf.y);
        float dpr = fmaf(o.x, rg.x, o.y * rg.y);

        float smax = fmaxf(fmaxf(dpu, dpd), fmaxf(dpl, dpr));
        float smin = fminf(fminf(dpu, dpd), fminf(dpl, dpr));

        psm[hr * SP + wc + PADP] = __floats2half2_rn(smax, smin);
    }
    __syncthreads();

    // ---- B: each thread owns 4 consecutive pixels of one row ----
    int r  = tid >> 4;          // 0..15
    int c  = tid & 15;          // 0..15 -> tile cols 4c..4c+3
    int h  = h0 + r;
    int wa = w0 + 4 * c;
    float* op = out + (size_t)n * 20 * HW + (size_t)h * IMG_W + wa;

    int pb  = r * SP + 4 * c + PADP;        // top window row, pair planes
    int ebn = (r + 1) * SP + 4 * c + PADP;  // top window row, en plane

    // Plain (cached) wide stores this round — isolating the nontemporal hint.
#define NTST(CH, V) *reinterpret_cast<vfloat4*>(&op[(size_t)(CH) * HW]) = (V)

    // -- {e0,e1} group: ch0,1 (+10,11) and derived m (ch2,12), cp (ch6,16) --
    {
        float ta[8], tb[8], ma[8], mb[8], ba[8], bb[8];
        loadrow8(&pe[pb],          ta, tb);
        loadrow8(&pe[pb + SP],     ma, mb);
        loadrow8(&pe[pb + 2 * SP], ba, bb);

        NTST(0, mk4(ma));  NTST(10, sobel4(ta, ma, ba));
        NTST(1, mk4(mb));  NTST(11, sobel4(tb, mb, bb));

        float tm[6], mm_[6], bm[6];
#pragma unroll
        for (int j = 0; j < 6; ++j) {
            tm[j]  = sqrt_fast(fmaf(ta[j], ta[j], tb[j] * tb[j]));
            mm_[j] = sqrt_fast(fmaf(ma[j], ma[j], mb[j] * mb[j]));
            bm[j]  = sqrt_fast(fmaf(ba[j], ba[j], bb[j] * bb[j]));
        }
        NTST(2, mk4(mm_)); NTST(12, sobel4(tm, mm_, bm));

        float tc[6], mc[6], bc[6];
#pragma unroll
        for (int j = 0; j < 6; ++j) {
            tc[j] = ta[j] * tb[j];
            mc[j] = ma[j] * mb[j];
            bc[j] = ba[j] * bb[j];
        }
        NTST(6, mk4(mc));  NTST(16, sobel4(tc, mc, bc));
    }

    // -- {ang,dl} group: ch3,7 (+13,17) --
    {
        float ta[8], tb[8], ma[8], mb[8], ba[8], bb[8];
        loadrow8(&pad2[pb],          ta, tb);
        loadrow8(&pad2[pb + SP],     ma, mb);
        loadrow8(&pad2[pb + 2 * SP], ba, bb);

        NTST(3, mk4(ma));  NTST(13, sobel4(ta, ma, ba));
        NTST(7, mk4(mb));  NTST(17, sobel4(tb, mb, bb));
    }

    // -- {smax,smin} group: ch8,9 (+18,19) --
    {
        float ta[8], tb[8], ma[8], mb[8], ba[8], bb[8];
        loadrow8(&psm[pb],          ta, tb);
        loadrow8(&psm[pb + SP],     ma, mb);
        loadrow8(&psm[pb + 2 * SP], ba, bb);

        NTST(8, mk4(ma));  NTST(18, sobel4(ta, ma, ba));
        NTST(9, mk4(mb));  NTST(19, sobel4(tb, mb, bb));
    }

    // -- {en0,en1} group: ch4,5 (+14,15); window shifted +1 within the ring --
    {
        float ta[8], tb[8], ma[8], mb[8], ba[8], bb[8];
        loadrow8(&lden[ebn],          ta, tb);
        loadrow8(&lden[ebn + SP],     ma, mb);
        loadrow8(&lden[ebn + 2 * SP], ba, bb);

        vfloat4 c4, c5;
        c4.x = ma[2]; c4.y = ma[3]; c4.z = ma[4]; c4.w = ma[5];
        c5.x = mb[2]; c5.y = mb[3]; c5.z = mb[4]; c5.w = mb[5];
        NTST(4, c4);  NTST(14, sobel4(ta + 1, ma + 1, ba + 1));
        NTST(5, c5);  NTST(15, sobel4(tb + 1, mb + 1, bb + 1));
    }
#undef NTST
}

extern "C" void kernel_launch(void* const* d_in, const int* in_sizes, int n_in,
                              void* d_out, int out_size, void* d_ws, size_t ws_size,
                              hipStream_t stream) {
    const float* x = (const float*)d_in[0];
    float* out = (float*)d_out;

    int grid = NIMG * TILES_H * TILES_W;   // 4096
    fused_kernel<<<grid, 256, 0, stream>>>(x, out);
}

// Round 10
// 69.999 us; speedup vs baseline: 1.2363x; 1.2363x over previous
//
#include <hip/hip_runtime.h>
#include <hip/hip_fp16.h>
#include <math.h>

#define IMG_H 512
#define IMG_W 512
#define NIMG  16
#define HW    (IMG_H * IMG_W)

#define TH 16
#define TW 64
#define HTH (TH + 2)          // 18 halo rows (pair planes)
#define HTW (TW + 2)          // 66 halo cols
#define ERH (TH + 4)          // 20 en-ring rows
#define ERW (TW + 4)          // 68 en-ring cols
#define SP  72                // stride (half2 units) for ALL planes; 288 B/row
#define PADP 4                // left pad (half2 units) -> b128 bases 16B-aligned
#define TILES_H (IMG_H / TH)  // 32
#define TILES_W (IMG_W / TW)  // 8

typedef float vfloat4 __attribute__((ext_vector_type(4)));

__device__ __forceinline__ float rcp_fast(float v) {
#if __has_builtin(__builtin_amdgcn_rcpf)
    return __builtin_amdgcn_rcpf(v);
#else
    return 1.0f / v;
#endif
}
__device__ __forceinline__ float rsq_fast(float v) {
#if __has_builtin(__builtin_amdgcn_rsqf)
    return __builtin_amdgcn_rsqf(v);
#else
    return rsqrtf(v);
#endif
}
__device__ __forceinline__ float sqrt_fast(float v) {
#if __has_builtin(__builtin_amdgcn_sqrtf)
    return __builtin_amdgcn_sqrtf(v);
#else
    return sqrtf(v);
#endif
}

// atan2 via polynomial; |err| ~1e-4 rad (abs threshold is 0.66).
__device__ __forceinline__ float fast_atan2f(float y, float x) {
    float ay = fabsf(y), ax = fabsf(x);
    float mx = fmaxf(ay, ax), mn = fminf(ay, ax);
    float a = mn * rcp_fast(mx);
    float s = a * a;
    float r = fmaf(fmaf(fmaf(0.0208351f, s, -0.085133f), s, 0.180141f), s, -0.3302995f);
    r = a * fmaf(r, s, 0.9998660f);
    if (ay > ax)  r = 1.57079632679f - r;
    if (x < 0.0f) r = 3.14159265359f - r;
    return copysignf(r, y);
}

// Load 8 consecutive half2 (16B-aligned) -> 8 "x" floats and 8 "y" floats.
__device__ __forceinline__ void loadrow8(const __half2* p, float* a, float* b) {
    union { vfloat4 v; __half2 h[4]; } u0, u1;
    u0.v = *reinterpret_cast<const vfloat4*>(p);
    u1.v = *reinterpret_cast<const vfloat4*>(p + 4);
#pragma unroll
    for (int j = 0; j < 4; ++j) {
        float2 f = __half22float2(u0.h[j]);
        a[j] = f.x; b[j] = f.y;
    }
#pragma unroll
    for (int j = 0; j < 4; ++j) {
        float2 f = __half22float2(u1.h[j]);
        a[4 + j] = f.x; b[4 + j] = f.y;
    }
}

// 6-wide rows -> 4 Sobel magnitudes.
__device__ __forceinline__ vfloat4 sobel4(const float* tt, const float* mm, const float* bb) {
    float vs[6], dd[6];
#pragma unroll
    for (int j = 0; j < 6; ++j) {
        vs[j] = tt[j] + fmaf(2.0f, mm[j], bb[j]);   // vertical [1,2,1] for gx
        dd[j] = bb[j] - tt[j];                       // vertical [-1,0,1] for gy
    }
    vfloat4 mag;
    float gx, gy;
    gx = vs[2] - vs[0]; gy = fmaf(2.f, dd[1], dd[0] + dd[2]);
    mag.x = sqrt_fast(fmaf(gx, gx, gy * gy));
    gx = vs[3] - vs[1]; gy = fmaf(2.f, dd[2], dd[1] + dd[3]);
    mag.y = sqrt_fast(fmaf(gx, gx, gy * gy));
    gx = vs[4] - vs[2]; gy = fmaf(2.f, dd[3], dd[2] + dd[4]);
    mag.z = sqrt_fast(fmaf(gx, gx, gy * gy));
    gx = vs[5] - vs[3]; gy = fmaf(2.f, dd[4], dd[3] + dd[5]);
    mag.w = sqrt_fast(fmaf(gx, gx, gy * gy));
    return mag;
}

__device__ __forceinline__ vfloat4 mk4(const float* m) {
    vfloat4 v; v.x = m[1]; v.y = m[2]; v.z = m[3]; v.w = m[4]; return v;
}

__global__ __launch_bounds__(256, 7) void fused_kernel(const float* __restrict__ x,
                                                       float* __restrict__ out) {
    // All planes interleaved half2, stride 72 half2 (288 B):
    //   lden: {en0,en1} on 20x68 ring  = 20*72*4 = 5760 B
    //   pe:   {e0,e1}   on 18x66 halo  = 18*72*4 = 5184 B
    //   pad2: {ang,dl}                 = 5184 B
    //   psm:  {smax,smin}              = 5184 B      total 21312 B -> 7 blocks/CU
    __shared__ __align__(16) __half2 lden[ERH * SP];
    __shared__ __align__(16) __half2 pe  [HTH * SP];
    __shared__ __align__(16) __half2 pad2[HTH * SP];
    __shared__ __align__(16) __half2 psm [HTH * SP];

    // XCD-contiguous swizzle: 4096 blocks % 8 XCDs == 0 -> bijective.
    int bid0 = blockIdx.x;
    int bid  = (bid0 & 7) * (NIMG * TILES_H * TILES_W / 8) + (bid0 >> 3);

    int n   = bid / (TILES_H * TILES_W);
    int t   = bid - n * (TILES_H * TILES_W);
    int th  = t / TILES_W;
    int tw  = t - th * TILES_W;
    int h0  = th * TH;
    int w0  = tw * TW;

    const float* xb = x + (size_t)n * 3 * HW;
    int tid = threadIdx.x;

    // ---- A1: en over the 20x68 ring; e/ang/dl planes over 18x66 ----
    for (int i = tid; i < ERH * ERW; i += 256) {
        int er = i / ERW;
        int ec = i - er * ERW;
        int h  = h0 + er - 2;
        int w  = w0 + ec - 2;
        bool inimg = (h >= 0) && (h < IMG_H) && (w >= 0) && (w < IMG_W);
        int rem = h * IMG_W + w;

        float e0 = 0.f, e1 = 0.f, en0 = 0.f, en1 = 0.f;
        if (inimg) {
            e0 = xb[rem];
            e1 = xb[HW + rem];
            float is = rsq_fast(fmaf(e0, e0, e1 * e1));
            en0 = e0 * is;
            en1 = e1 * is;
        }
        lden[er * SP + ec + PADP] = __floats2half2_rn(en0, en1);

        int hr = er - 1, wc = ec - 1;
        if (hr >= 0 && hr < HTH && wc >= 0 && wc < HTW) {
            float dl = 0.f, ang = 0.f;
            if (inimg) {
                dl  = xb[2 * HW + rem];
                ang = 0.5f * fast_atan2f(e0, e1);
            }
            pe  [hr * SP + wc + PADP] = __floats2half2_rn(e0, e1);
            pad2[hr * SP + wc + PADP] = __floats2half2_rn(ang, dl);
        }
    }
    __syncthreads();

    // ---- A2: neighbor similarity (smax/smin) from the en plane ----
    for (int i = tid; i < HTH * HTW; i += 256) {
        int hr = i / HTW;
        int wc = i - hr * HTW;
        int eb = (hr + 1) * SP + (wc + 1) + PADP;

        float2 o  = __half22float2(lden[eb]);
        float2 u  = __half22float2(lden[eb + SP]);   // h+1
        float2 d  = __half22float2(lden[eb - SP]);   // h-1
        float2 lf = __half22float2(lden[eb + 1]);    // w+1
        float2 rg = __half22float2(lden[eb - 1]);    // w-1

        float dpu = fmaf(o.x, u.x,  o.y * u.y);
        float dpd = fmaf(o.x, d.x,  o.y * d.y);
        float dpl = fmaf(o.x, lf.x, o.y * lf.y);
        float dpr = fmaf(o.x, rg.x, o.y * rg.y);

        float smax = fmaxf(fmaxf(dpu, dpd), fmaxf(dpl, dpr));
        float smin = fminf(fminf(dpu, dpd), fminf(dpl, dpr));

        psm[hr * SP + wc + PADP] = __floats2half2_rn(smax, smin);
    }
    __syncthreads();

    // ---- B: each thread owns 4 consecutive pixels of one row ----
    int r  = tid >> 4;          // 0..15
    int c  = tid & 15;          // 0..15 -> tile cols 4c..4c+3
    int h  = h0 + r;
    int wa = w0 + 4 * c;
    float* op = out + (size_t)n * 20 * HW + (size_t)h * IMG_W + wa;

    int pb  = r * SP + 4 * c + PADP;        // top window row, pair planes
    int ebn = (r + 1) * SP + 4 * c + PADP;  // top window row, en plane

    // Nontemporal stores: R9 A/B showed they are worth ~16 us (86.5 -> 70.2).
#define NTST(CH, V) __builtin_nontemporal_store((V), reinterpret_cast<vfloat4*>(&op[(size_t)(CH) * HW]))

    // -- {e0,e1} group: ch0,1 (+10,11) and derived m (ch2,12), cp (ch6,16) --
    {
        float ta[8], tb[8], ma[8], mb[8], ba[8], bb[8];
        loadrow8(&pe[pb],          ta, tb);
        loadrow8(&pe[pb + SP],     ma, mb);
        loadrow8(&pe[pb + 2 * SP], ba, bb);

        NTST(0, mk4(ma));  NTST(10, sobel4(ta, ma, ba));
        NTST(1, mk4(mb));  NTST(11, sobel4(tb, mb, bb));

        float tm[6], mm_[6], bm[6];
#pragma unroll
        for (int j = 0; j < 6; ++j) {
            tm[j]  = sqrt_fast(fmaf(ta[j], ta[j], tb[j] * tb[j]));
            mm_[j] = sqrt_fast(fmaf(ma[j], ma[j], mb[j] * mb[j]));
            bm[j]  = sqrt_fast(fmaf(ba[j], ba[j], bb[j] * bb[j]));
        }
        NTST(2, mk4(mm_)); NTST(12, sobel4(tm, mm_, bm));

        float tc[6], mc[6], bc[6];
#pragma unroll
        for (int j = 0; j < 6; ++j) {
            tc[j] = ta[j] * tb[j];
            mc[j] = ma[j] * mb[j];
            bc[j] = ba[j] * bb[j];
        }
        NTST(6, mk4(mc));  NTST(16, sobel4(tc, mc, bc));
    }

    // -- {ang,dl} group: ch3,7 (+13,17) --
    {
        float ta[8], tb[8], ma[8], mb[8], ba[8], bb[8];
        loadrow8(&pad2[pb],          ta, tb);
        loadrow8(&pad2[pb + SP],     ma, mb);
        loadrow8(&pad2[pb + 2 * SP], ba, bb);

        NTST(3, mk4(ma));  NTST(13, sobel4(ta, ma, ba));
        NTST(7, mk4(mb));  NTST(17, sobel4(tb, mb, bb));
    }

    // -- {smax,smin} group: ch8,9 (+18,19) --
    {
        float ta[8], tb[8], ma[8], mb[8], ba[8], bb[8];
        loadrow8(&psm[pb],          ta, tb);
        loadrow8(&psm[pb + SP],     ma, mb);
        loadrow8(&psm[pb + 2 * SP], ba, bb);

        NTST(8, mk4(ma));  NTST(18, sobel4(ta, ma, ba));
        NTST(9, mk4(mb));  NTST(19, sobel4(tb, mb, bb));
    }

    // -- {en0,en1} group: ch4,5 (+14,15); window shifted +1 within the ring --
    {
        float ta[8], tb[8], ma[8], mb[8], ba[8], bb[8];
        loadrow8(&lden[ebn],          ta, tb);
        loadrow8(&lden[ebn + SP],     ma, mb);
        loadrow8(&lden[ebn + 2 * SP], ba, bb);

        vfloat4 c4, c5;
        c4.x = ma[2]; c4.y = ma[3]; c4.z = ma[4]; c4.w = ma[5];
        c5.x = mb[2]; c5.y = mb[3]; c5.z = mb[4]; c5.w = mb[5];
        NTST(4, c4);  NTST(14, sobel4(ta + 1, ma + 1, ba + 1));
        NTST(5, c5);  NTST(15, sobel4(tb + 1, mb + 1, bb + 1));
    }
#undef NTST
}

extern "C" void kernel_launch(void* const* d_in, const int* in_sizes, int n_in,
                              void* d_out, int out_size, void* d_ws, size_t ws_size,
                              hipStream_t stream) {
    const float* x = (const float*)d_in[0];
    float* out = (float*)d_out;

    int grid = NIMG * TILES_H * TILES_W;   // 4096
    fused_kernel<<<grid, 256, 0, stream>>>(x, out);
}